// Round 8
// baseline (150.662 us; speedup 1.0000x reference)
//
#include <hip/hip_runtime.h>
#include <cstddef>

#define B_     4
#define NTOK   1024
#define DMODEL 768
#define NH     12
#define IMGC   256
#define NPIX   1024

typedef __attribute__((ext_vector_type(8))) short bf16x8;
typedef __attribute__((ext_vector_type(4))) float f32x4;
typedef __attribute__((ext_vector_type(8))) unsigned short u16x8;

static __device__ __forceinline__ unsigned short f2bf(float f) {
  unsigned int u = __float_as_uint(f);
  u += 0x7FFFu + ((u >> 16) & 1u);
  return (unsigned short)(u >> 16);
}

// swizzled LDS byte address: 128B rows, XOR bits 4..6 with row&7
#define SWZ(row, b) (((row) << 7) + ((b) ^ (((row) & 7) << 4)))

#define GLOAD16(g, l) __builtin_amdgcn_global_load_lds(                      \
    (const __attribute__((address_space(1))) void*)(g),                      \
    (__attribute__((address_space(3))) void*)(l), 16, 0, 0)

// ---------------- K0: merged preprocessing.
// blocks [0,1536): X->Xb ; [1536,3264): Wqkv^T->Wtb ; [3264,3360): W2->W2b ;
// 3360: zero bn accumulators ; [3361,3873): depthwise3x3 + transpose -> y1t bf16
__global__ __launch_bounds__(256) void k_pre(const float* __restrict__ X,
                                             const float* __restrict__ Wqkv,
                                             const float* __restrict__ W2,
                                             const float* __restrict__ Yimg,
                                             const float* __restrict__ w1,
                                             unsigned short* __restrict__ Xb,
                                             unsigned short* __restrict__ Wtb,
                                             unsigned short* __restrict__ W2b,
                                             unsigned short* __restrict__ y1t,
                                             float* __restrict__ bnacc) {
  __shared__ unsigned short T[32][33];
  __shared__ float Ts[32][65];
  const int bid = blockIdx.x;
  const int t = threadIdx.x;
  if (bid < 1536) {
    const size_t i8 = (size_t)bid * 256 + t;
    const float4 a = *(const float4*)(X + i8 * 8);
    const float4 b = *(const float4*)(X + i8 * 8 + 4);
    u16x8 o;
    o[0] = f2bf(a.x); o[1] = f2bf(a.y); o[2] = f2bf(a.z); o[3] = f2bf(a.w);
    o[4] = f2bf(b.x); o[5] = f2bf(b.y); o[6] = f2bf(b.z); o[7] = f2bf(b.w);
    *(u16x8*)(Xb + i8 * 8) = o;
  } else if (bid < 3264) {
    const int b2 = bid - 1536;
    const int n0 = (b2 % 72) * 32, k0 = (b2 / 72) * 32;
    const int tx = t & 31, ty = t >> 5;
#pragma unroll
    for (int i = 0; i < 4; i++) {
      int kl = ty + i * 8;
      T[tx][kl] = f2bf(Wqkv[(size_t)(k0 + kl) * 2304 + n0 + tx]);
    }
    __syncthreads();
#pragma unroll
    for (int i = 0; i < 4; i++) {
      int nl = ty + i * 8;
      Wtb[(size_t)(n0 + nl) * 768 + k0 + tx] = T[nl][tx];
    }
  } else if (bid < 3360) {
    const size_t i8 = (size_t)(bid - 3264) * 256 + t;
    const float4 a = *(const float4*)(W2 + i8 * 8);
    const float4 b = *(const float4*)(W2 + i8 * 8 + 4);
    u16x8 o;
    o[0] = f2bf(a.x); o[1] = f2bf(a.y); o[2] = f2bf(a.z); o[3] = f2bf(a.w);
    o[4] = f2bf(b.x); o[5] = f2bf(b.y); o[6] = f2bf(b.z); o[7] = f2bf(b.w);
    *(u16x8*)(W2b + i8 * 8) = o;
  } else if (bid == 3360) {
    for (int i = t; i < 1536; i += 256) bnacc[i] = 0.0f;
  } else {
    // depthwise 3x3 + bf16 transpose: block = (b, 32-ch group, 2-row strip)
    const int db = bid - 3361;            // 0..511
    const int b  = db >> 7;               // /128 -> 0..3
    const int cg = (db >> 4) & 7;         // 0..7
    const int ps = db & 15;               // 0..15 (2 rows each)
    const int cl = t >> 3, sub = t & 7;
    const int c  = cg * 32 + cl;
    const int row = ps * 2 + (sub >> 2);  // global image row
    const int xx0 = (sub & 3) * 8;
    const float* yin = Yimg + ((size_t)(b * 256 + c) << 10);
    float wv[9];
#pragma unroll
    for (int i = 0; i < 9; i++) wv[i] = w1[c * 9 + i];
#pragma unroll
    for (int i = 0; i < 8; i++) {
      const int xx = xx0 + i;
      float a = 0.0f;
#pragma unroll
      for (int dy = -1; dy <= 1; dy++) {
        const int sy = row + dy;
        if (sy < 0 || sy > 31) continue;
#pragma unroll
        for (int dx = -1; dx <= 1; dx++) {
          const int sx = xx + dx;
          if (sx < 0 || sx > 31) continue;
          a = fmaf(yin[(sy << 5) + sx], wv[(dy + 1) * 3 + dx + 1], a);
        }
      }
      Ts[cl][(sub >> 2) * 32 + xx] = a;
    }
    __syncthreads();
    const int cl2 = t & 31, pidx = t >> 5;
    unsigned short* dst = y1t + ((size_t)b << 18) + (size_t)(ps * 64) * 256 + cg * 32;
#pragma unroll
    for (int i = 0; i < 8; i++) {
      const int p = pidx * 8 + i;        // 0..63 within strip
      dst[(size_t)p * 256 + cl2] = f2bf(Ts[cl2][p]);
    }
  }
}

// ---------------- K1: QKV GEMM bf16 MFMA (single-buffer, round-4 structure)
__global__ __launch_bounds__(256) void k_qkv_gemm(const unsigned short* __restrict__ Xb,
                                                  const unsigned short* __restrict__ Wt,
                                                  unsigned short* __restrict__ q,
                                                  unsigned short* __restrict__ k,
                                                  unsigned short* __restrict__ v) {
  __shared__ __align__(16) char AsB[16384];
  __shared__ __align__(16) char BsB[16384];
  const int t = threadIdx.x;
  const int w = t >> 6, l = t & 63;
  const int r = l & 15, g = l >> 4;
  const int wr = w >> 1, wc = w & 1;
  const int m0 = blockIdx.y * 128;
  const int n0 = blockIdx.x * 128;
  const int rsel  = l >> 3;
  const int slotp = (l & 7) ^ (rsel & 7);
  f32x4 acc[4][4] = {};

  for (int step = 0; step < 12; ++step) {
    const int k0 = step * 64;
#pragma unroll
    for (int i = 0; i < 4; i++) {
      const int chunk = (i << 2) + w;
      const int row = (chunk << 3) + rsel;
      GLOAD16(Xb + (size_t)(m0 + row) * 768 + k0 + (slotp << 3),
              AsB + (chunk << 10) + (l << 4));
      GLOAD16(Wt + (size_t)(n0 + row) * 768 + k0 + (slotp << 3),
              BsB + (chunk << 10) + (l << 4));
    }
    __syncthreads();
#pragma unroll
    for (int kk = 0; kk < 2; kk++) {
      bf16x8 a[4], b[4];
#pragma unroll
      for (int m = 0; m < 4; m++) {
        const int row = wr * 64 + m * 16 + r;
        a[m] = *(const bf16x8*)(AsB + SWZ(row, kk * 64 + (g << 4)));
      }
#pragma unroll
      for (int n = 0; n < 4; n++) {
        const int row = wc * 64 + n * 16 + r;
        b[n] = *(const bf16x8*)(BsB + SWZ(row, kk * 64 + (g << 4)));
      }
#pragma unroll
      for (int m = 0; m < 4; m++)
#pragma unroll
        for (int n = 0; n < 4; n++)
          acc[m][n] = __builtin_amdgcn_mfma_f32_16x16x32_bf16(a[m], b[n], acc[m][n], 0, 0, 0);
    }
    __syncthreads();
  }

  const int which = blockIdx.x / 6;
  const int cbase = (blockIdx.x - which * 6) * 128 + wc * 64;
  unsigned short* dst = which == 0 ? q : (which == 1 ? k : v);
#pragma unroll
  for (int m = 0; m < 4; m++) {
    const int grow = m0 + wr * 64 + m * 16 + g * 4;
#pragma unroll
    for (int n = 0; n < 4; n++) {
      const int c = cbase + n * 16 + r;
      const int head = c >> 6, dim = c & 63;
#pragma unroll
      for (int reg = 0; reg < 4; reg++) {
        const int row = grow + reg;
        const int bb = row >> 10, tok = row & 1023;
        dst[((size_t)(((bb * NH + head) << 10) + tok) << 6) + dim] = f2bf(acc[m][n][reg]);
      }
    }
  }
}

// ---------------- K2: flash attention, bf16 MFMA (exact round-4 structure)
__global__ __launch_bounds__(256) void k_attn(const unsigned short* __restrict__ qb,
                                              const unsigned short* __restrict__ kb,
                                              const unsigned short* __restrict__ vb,
                                              const float* __restrict__ dm,
                                              float* __restrict__ out0) {
  __shared__ __align__(16) unsigned short QsA[4096];
  __shared__ __align__(16) unsigned short KsA[4096];
  __shared__ __align__(16) unsigned short VtA[4096];
  __shared__ __align__(16) unsigned short PsA[4096];
  char* qs = (char*)QsA; char* ks = (char*)KsA;
  char* vt = (char*)VtA; char* ps = (char*)PsA;
  const int bh = blockIdx.x;
  const int qt = blockIdx.y;
  const int t  = threadIdx.x;
  const int w = t >> 6, l = t & 63, r = l & 15, g = l >> 4;
  const size_t hbase = (size_t)bh << 16;
  const char* qg = (const char*)(qb + hbase + ((size_t)qt << 12));
  const char* kg = (const char*)(kb + hbase);
  const char* vg = (const char*)(vb + hbase);
  const float* mp = dm + ((size_t)bh << 20) + ((size_t)(qt * 64) << 10);

#pragma unroll
  for (int i = 0; i < 2; i++) {
    int cid = t + (i << 8);
    int row = cid >> 3, slot = cid & 7;
    uint4 val = *(const uint4*)(qg + row * 128 + slot * 16);
    *(uint4*)(qs + SWZ(row, slot * 16)) = val;
  }

  float m_run[4] = {-INFINITY, -INFINITY, -INFINITY, -INFINITY};
  float l_run[4] = {0.0f, 0.0f, 0.0f, 0.0f};
  f32x4 O[4] = {};

  for (int kt = 0; kt < 16; kt++) {
    __syncthreads();
#pragma unroll
    for (int i = 0; i < 2; i++) {
      int cid = t + (i << 8);
      int row = cid >> 3, slot = cid & 7;
      uint4 val = *(const uint4*)(kg + (size_t)(kt * 64 + row) * 128 + slot * 16);
      *(uint4*)(ks + SWZ(row, slot * 16)) = val;
    }
    {
      int j = t & 63, dh = t >> 6;
      const char* vrow = vg + (size_t)(kt * 64 + j) * 128 + dh * 32;
      u16x8 v0 = *(const u16x8*)(vrow);
      u16x8 v1 = *(const u16x8*)(vrow + 16);
#pragma unroll
      for (int e = 0; e < 8; e++) {
        *(unsigned short*)(vt + SWZ(dh * 16 + e, 2 * j))     = v0[e];
        *(unsigned short*)(vt + SWZ(dh * 16 + 8 + e, 2 * j)) = v1[e];
      }
    }
    float md[4][4];
    {
      const float* mr = mp + (size_t)(w * 16 + g * 4) * 1024 + kt * 64 + r;
#pragma unroll
      for (int reg = 0; reg < 4; reg++)
#pragma unroll
        for (int jt = 0; jt < 4; jt++)
          md[reg][jt] = mr[reg * 1024 + jt * 16];
    }
    __syncthreads();

    f32x4 s[4] = {};
    bf16x8 aQ[2];
#pragma unroll
    for (int kc = 0; kc < 2; kc++)
      aQ[kc] = *(const bf16x8*)(qs + SWZ(w * 16 + r, kc * 64 + g * 16));
#pragma unroll
    for (int jt = 0; jt < 4; jt++) {
#pragma unroll
      for (int kc = 0; kc < 2; kc++) {
        bf16x8 bK = *(const bf16x8*)(ks + SWZ(jt * 16 + r, kc * 64 + g * 16));
        s[jt] = __builtin_amdgcn_mfma_f32_16x16x32_bf16(aQ[kc], bK, s[jt], 0, 0, 0);
      }
    }
    float sv[4][4];
#pragma unroll
    for (int jt = 0; jt < 4; jt++)
#pragma unroll
      for (int reg = 0; reg < 4; reg++)
        sv[jt][reg] = s[jt][reg] * 0.125f + (md[reg][jt] < 0.1f ? -1e12f : 0.0f);

    float alpha[4];
#pragma unroll
    for (int reg = 0; reg < 4; reg++) {
      float mt = fmaxf(fmaxf(sv[0][reg], sv[1][reg]), fmaxf(sv[2][reg], sv[3][reg]));
      mt = fmaxf(mt, __shfl_xor(mt, 1));
      mt = fmaxf(mt, __shfl_xor(mt, 2));
      mt = fmaxf(mt, __shfl_xor(mt, 4));
      mt = fmaxf(mt, __shfl_xor(mt, 8));
      float mn = fmaxf(m_run[reg], mt);
      alpha[reg] = __expf(m_run[reg] - mn);
      m_run[reg] = mn;
    }
#pragma unroll
    for (int reg = 0; reg < 4; reg++) {
      int row = w * 16 + g * 4 + reg;
      float ps_ = 0.0f;
#pragma unroll
      for (int jt = 0; jt < 4; jt++) {
        float p = __expf(sv[jt][reg] - m_run[reg]);
        ps_ += p;
        *(unsigned short*)(ps + SWZ(row, 2 * (jt * 16 + r))) = f2bf(p);
      }
      ps_ += __shfl_xor(ps_, 1);
      ps_ += __shfl_xor(ps_, 2);
      ps_ += __shfl_xor(ps_, 4);
      ps_ += __shfl_xor(ps_, 8);
      l_run[reg] = l_run[reg] * alpha[reg] + ps_;
    }
#pragma unroll
    for (int dt = 0; dt < 4; dt++)
#pragma unroll
      for (int reg = 0; reg < 4; reg++)
        O[dt][reg] *= alpha[reg];
    asm volatile("s_waitcnt lgkmcnt(0)" ::: "memory");
    __builtin_amdgcn_sched_barrier(0);
#pragma unroll
    for (int kc = 0; kc < 2; kc++) {
      bf16x8 aP = *(const bf16x8*)(ps + SWZ(w * 16 + r, kc * 64 + g * 16));
#pragma unroll
      for (int dt = 0; dt < 4; dt++) {
        bf16x8 bV = *(const bf16x8*)(vt + SWZ(dt * 16 + r, kc * 64 + g * 16));
        O[dt] = __builtin_amdgcn_mfma_f32_16x16x32_bf16(aP, bV, O[dt], 0, 0, 0);
      }
    }
  }
  const int bb = bh / NH, hh = bh % NH;
  float inv[4];
#pragma unroll
  for (int reg = 0; reg < 4; reg++) inv[reg] = 1.0f / l_run[reg];
  float* op = out0 + ((size_t)(bb * 1024 + qt * 64 + w * 16 + g * 4)) * 768 + hh * 64 + r;
#pragma unroll
  for (int reg = 0; reg < 4; reg++)
#pragma unroll
    for (int dt = 0; dt < 4; dt++)
      op[(size_t)reg * 768 + dt * 16] = O[dt][reg] * inv[reg];
}

// ---------------- K4: 1x1 conv bf16 MFMA (single-buffer); fused BN partials
__global__ __launch_bounds__(256) void k_c1x1(const unsigned short* __restrict__ W2b,
                                              const unsigned short* __restrict__ y1t,
                                              float* __restrict__ Y2,
                                              float* __restrict__ bn_sum,
                                              float* __restrict__ bn_sumsq) {
  __shared__ __align__(16) char AsB[16384];
  __shared__ __align__(16) char BsB[16384];
  const int t = threadIdx.x;
  const int w = t >> 6, l = t & 63;
  const int r = l & 15, g = l >> 4;
  const int wr = w >> 1, wc = w & 1;
  const int m0 = blockIdx.y * 128;
  const int n0 = blockIdx.x * 128;
  const int b  = blockIdx.z;
  const unsigned short* Bb = y1t + ((size_t)b << 18);
  const int rsel  = l >> 3;
  const int slotp = (l & 7) ^ (rsel & 7);
  f32x4 acc[4][4] = {};

  for (int step = 0; step < 4; ++step) {
    const int k0 = step * 64;
#pragma unroll
    for (int i = 0; i < 4; i++) {
      const int chunk = (i << 2) + w;
      const int row = (chunk << 3) + rsel;
      GLOAD16(W2b + (size_t)(m0 + row) * 256 + k0 + (slotp << 3),
              AsB + (chunk << 10) + (l << 4));
      GLOAD16(Bb + (size_t)(n0 + row) * 256 + k0 + (slotp << 3),
              BsB + (chunk << 10) + (l << 4));
    }
    __syncthreads();
#pragma unroll
    for (int kk = 0; kk < 2; kk++) {
      bf16x8 a[4], bfr[4];
#pragma unroll
      for (int m = 0; m < 4; m++) {
        const int row = wr * 64 + m * 16 + r;
        a[m] = *(const bf16x8*)(AsB + SWZ(row, kk * 64 + (g << 4)));
      }
#pragma unroll
      for (int n = 0; n < 4; n++) {
        const int row = wc * 64 + n * 16 + r;
        bfr[n] = *(const bf16x8*)(BsB + SWZ(row, kk * 64 + (g << 4)));
      }
#pragma unroll
      for (int m = 0; m < 4; m++)
#pragma unroll
        for (int n = 0; n < 4; n++)
          acc[m][n] = __builtin_amdgcn_mfma_f32_16x16x32_bf16(a[m], bfr[n], acc[m][n], 0, 0, 0);
    }
    __syncthreads();
  }

  float* Yb = Y2 + (((size_t)b * DMODEL) << 10);
#pragma unroll
  for (int m = 0; m < 4; m++) {
#pragma unroll
    for (int reg = 0; reg < 4; reg++) {
      const int oc = m0 + wr * 64 + m * 16 + g * 4 + reg;
      float s = 0.0f, sq = 0.0f;
#pragma unroll
      for (int n = 0; n < 4; n++) {
        const int p = n0 + wc * 64 + n * 16 + r;
        const float val = acc[m][n][reg];
        Yb[((size_t)oc << 10) + p] = val;
        s += val;
        sq = fmaf(val, val, sq);
      }
      s  += __shfl_xor(s, 1);  sq += __shfl_xor(sq, 1);
      s  += __shfl_xor(s, 2);  sq += __shfl_xor(sq, 2);
      s  += __shfl_xor(s, 4);  sq += __shfl_xor(sq, 4);
      s  += __shfl_xor(s, 8);  sq += __shfl_xor(sq, 8);
      if (r == 0) {
        atomicAdd(&bn_sum[oc], s);
        atomicAdd(&bn_sumsq[oc], sq);
      }
    }
  }
}

// ---------------- K6: scale/shift from sums, BN+ReLU -> out1, transpose-add into out0
__global__ __launch_bounds__(256) void k_bnfuse(const float* __restrict__ y2,
                                                const float* __restrict__ bn_sum,
                                                const float* __restrict__ bn_sumsq,
                                                const float* __restrict__ gamma,
                                                const float* __restrict__ beta,
                                                float* __restrict__ out0,
                                                float* __restrict__ out1) {
  __shared__ float T[32][33];
  __shared__ float sc_l[32], sh_l[32];
  const int p0 = blockIdx.x * 32;
  const int c0 = blockIdx.y * 32;
  const int bb = blockIdx.z;
  const int tx = threadIdx.x;
  const int ty = threadIdx.y;
  const int tt = ty * 32 + tx;
  if (tt < 32) {
    const int c = c0 + tt;
    float S = bn_sum[c], SQ = bn_sumsq[c];
    float mean = S * (1.0f / 4096.0f);
    float var = SQ * (1.0f / 4096.0f) - mean * mean;
    float rstd = rsqrtf(var + 1e-5f);
    float s = gamma[c] * rstd;
    sc_l[tt] = s;
    sh_l[tt] = fmaf(-mean, s, beta[c]);
  }
  __syncthreads();
#pragma unroll
  for (int i = 0; i < 4; i++) {
    int cl = ty + 8 * i;
    int c = c0 + cl;
    size_t a = ((size_t)(bb * DMODEL + c) << 10) + p0 + tx;
    float val = fmaxf(fmaf(y2[a], sc_l[cl], sh_l[cl]), 0.0f);
    out1[a] = val;
    T[cl][tx] = val;
  }
  __syncthreads();
#pragma unroll
  for (int i = 0; i < 4; i++) {
    int pl = ty + 8 * i;
    size_t a = ((size_t)((bb << 10) + p0 + pl)) * DMODEL + c0 + tx;
    out0[a] += T[tx][pl];
  }
}

extern "C" void kernel_launch(void* const* d_in, const int* in_sizes, int n_in,
                              void* d_out, int out_size, void* d_ws, size_t ws_size,
                              hipStream_t stream) {
  (void)in_sizes; (void)n_in; (void)out_size; (void)ws_size;
  const float* x    = (const float*)d_in[0];
  const float* y    = (const float*)d_in[1];
  const float* dm   = (const float*)d_in[2];
  const float* wqkv = (const float*)d_in[3];
  const float* w1   = (const float*)d_in[4];
  const float* w2   = (const float*)d_in[5];
  const float* gam  = (const float*)d_in[6];
  const float* bet  = (const float*)d_in[7];
  float* out0 = (float*)d_out;
  float* out1 = out0 + (size_t)B_ * NTOK * DMODEL;

  char* wsb = (char*)d_ws;
  unsigned short* Xb  = (unsigned short*)wsb;
  unsigned short* Wtb = (unsigned short*)(wsb + 6291456);
  unsigned short* W2b = (unsigned short*)(wsb + 9830400);
  unsigned short* qb  = (unsigned short*)(wsb + 10223616);
  unsigned short* kb  = (unsigned short*)(wsb + 16515072);
  unsigned short* vb  = (unsigned short*)(wsb + 22806528);
  unsigned short* y1t = (unsigned short*)(wsb + 29097984);
  float* y2 = (float*)(wsb + 31195136);
  float* bnacc = (float*)(wsb + 43778048);
  float* bn_sum = bnacc;
  float* bn_sumsq = bnacc + 768;

  k_pre<<<dim3(3873), 256, 0, stream>>>(x, wqkv, w2, y, w1, Xb, Wtb, W2b, y1t, bnacc);
  k_c1x1<<<dim3(8, 6, B_), 256, 0, stream>>>(W2b, y1t, y2, bn_sum, bn_sumsq);
  k_qkv_gemm<<<dim3(18, 32), 256, 0, stream>>>(Xb, Wtb, qb, kb, vb);
  k_attn<<<dim3(48, 16), 256, 0, stream>>>(qb, kb, vb, dm, out0);
  k_bnfuse<<<dim3(32, 24, B_), dim3(32, 8), 0, stream>>>(y2, bn_sum, bn_sumsq, gam, bet, out0, out1);
}

// Round 9
// 139.889 us; speedup vs baseline: 1.0770x; 1.0770x over previous
//
#include <hip/hip_runtime.h>
#include <cstddef>

#define B_     4
#define NTOK   1024
#define DMODEL 768
#define NH     12
#define IMGC   256
#define NPIX   1024

typedef __attribute__((ext_vector_type(8))) short bf16x8;
typedef __attribute__((ext_vector_type(4))) float f32x4;
typedef __attribute__((ext_vector_type(8))) unsigned short u16x8;

static __device__ __forceinline__ unsigned short f2bf(float f) {
  unsigned int u = __float_as_uint(f);
  u += 0x7FFFu + ((u >> 16) & 1u);
  return (unsigned short)(u >> 16);
}

// swizzled LDS byte address: 128B rows, XOR bits 4..6 with row&7
#define SWZ(row, b) (((row) << 7) + ((b) ^ (((row) & 7) << 4)))

#define GLOAD16(g, l) __builtin_amdgcn_global_load_lds(                      \
    (const __attribute__((address_space(1))) void*)(g),                      \
    (__attribute__((address_space(3))) void*)(l), 16, 0, 0)

// ---------------- K0: merged converts + BN-accumulator zeroing (round-4)
__global__ __launch_bounds__(256) void k_cvt(const float* __restrict__ X,
                                             const float* __restrict__ Wqkv,
                                             const float* __restrict__ W2,
                                             unsigned short* __restrict__ Xb,
                                             unsigned short* __restrict__ Wtb,
                                             unsigned short* __restrict__ W2b,
                                             float* __restrict__ bnacc) {
  __shared__ unsigned short T[32][33];
  const int bid = blockIdx.x;
  const int t = threadIdx.x;
  if (bid < 1536) {
    const size_t i8 = (size_t)bid * 256 + t;
    const float4 a = *(const float4*)(X + i8 * 8);
    const float4 b = *(const float4*)(X + i8 * 8 + 4);
    u16x8 o;
    o[0] = f2bf(a.x); o[1] = f2bf(a.y); o[2] = f2bf(a.z); o[3] = f2bf(a.w);
    o[4] = f2bf(b.x); o[5] = f2bf(b.y); o[6] = f2bf(b.z); o[7] = f2bf(b.w);
    *(u16x8*)(Xb + i8 * 8) = o;
  } else if (bid < 3264) {
    const int b2 = bid - 1536;
    const int n0 = (b2 % 72) * 32, k0 = (b2 / 72) * 32;
    const int tx = t & 31, ty = t >> 5;
#pragma unroll
    for (int i = 0; i < 4; i++) {
      int kl = ty + i * 8;
      T[tx][kl] = f2bf(Wqkv[(size_t)(k0 + kl) * 2304 + n0 + tx]);
    }
    __syncthreads();
#pragma unroll
    for (int i = 0; i < 4; i++) {
      int nl = ty + i * 8;
      Wtb[(size_t)(n0 + nl) * 768 + k0 + tx] = T[nl][tx];
    }
  } else if (bid < 3360) {
    const size_t i8 = (size_t)(bid - 3264) * 256 + t;
    const float4 a = *(const float4*)(W2 + i8 * 8);
    const float4 b = *(const float4*)(W2 + i8 * 8 + 4);
    u16x8 o;
    o[0] = f2bf(a.x); o[1] = f2bf(a.y); o[2] = f2bf(a.z); o[3] = f2bf(a.w);
    o[4] = f2bf(b.x); o[5] = f2bf(b.y); o[6] = f2bf(b.z); o[7] = f2bf(b.w);
    *(u16x8*)(W2b + i8 * 8) = o;
  } else {
    for (int i = t; i < 1536; i += 256) bnacc[i] = 0.0f;
  }
}

// ---------------- K1: QKV GEMM bf16 MFMA (round-4 single-buffer)
__global__ __launch_bounds__(256) void k_qkv_gemm(const unsigned short* __restrict__ Xb,
                                                  const unsigned short* __restrict__ Wt,
                                                  unsigned short* __restrict__ q,
                                                  unsigned short* __restrict__ k,
                                                  unsigned short* __restrict__ v) {
  __shared__ __align__(16) char AsB[16384];
  __shared__ __align__(16) char BsB[16384];
  const int t = threadIdx.x;
  const int w = t >> 6, l = t & 63;
  const int r = l & 15, g = l >> 4;
  const int wr = w >> 1, wc = w & 1;
  const int m0 = blockIdx.y * 128;
  const int n0 = blockIdx.x * 128;
  const int rsel  = l >> 3;
  const int slotp = (l & 7) ^ (rsel & 7);
  f32x4 acc[4][4] = {};

  for (int step = 0; step < 12; ++step) {
    const int k0 = step * 64;
#pragma unroll
    for (int i = 0; i < 4; i++) {
      const int chunk = (i << 2) + w;
      const int row = (chunk << 3) + rsel;
      GLOAD16(Xb + (size_t)(m0 + row) * 768 + k0 + (slotp << 3),
              AsB + (chunk << 10) + (l << 4));
      GLOAD16(Wt + (size_t)(n0 + row) * 768 + k0 + (slotp << 3),
              BsB + (chunk << 10) + (l << 4));
    }
    __syncthreads();
#pragma unroll
    for (int kk = 0; kk < 2; kk++) {
      bf16x8 a[4], b[4];
#pragma unroll
      for (int m = 0; m < 4; m++) {
        const int row = wr * 64 + m * 16 + r;
        a[m] = *(const bf16x8*)(AsB + SWZ(row, kk * 64 + (g << 4)));
      }
#pragma unroll
      for (int n = 0; n < 4; n++) {
        const int row = wc * 64 + n * 16 + r;
        b[n] = *(const bf16x8*)(BsB + SWZ(row, kk * 64 + (g << 4)));
      }
#pragma unroll
      for (int m = 0; m < 4; m++)
#pragma unroll
        for (int n = 0; n < 4; n++)
          acc[m][n] = __builtin_amdgcn_mfma_f32_16x16x32_bf16(a[m], b[n], acc[m][n], 0, 0, 0);
    }
    __syncthreads();
  }

  const int which = blockIdx.x / 6;
  const int cbase = (blockIdx.x - which * 6) * 128 + wc * 64;
  unsigned short* dst = which == 0 ? q : (which == 1 ? k : v);
#pragma unroll
  for (int m = 0; m < 4; m++) {
    const int grow = m0 + wr * 64 + m * 16 + g * 4;
#pragma unroll
    for (int n = 0; n < 4; n++) {
      const int c = cbase + n * 16 + r;
      const int head = c >> 6, dim = c & 63;
#pragma unroll
      for (int reg = 0; reg < 4; reg++) {
        const int row = grow + reg;
        const int bb = row >> 10, tok = row & 1023;
        dst[((size_t)(((bb * NH + head) << 10) + tok) << 6) + dim] = f2bf(acc[m][n][reg]);
      }
    }
  }
}

// ---------------- K2: flash attention (round-4 structure; mask via float4+bitpack+shfl)
__global__ __launch_bounds__(256) void k_attn(const unsigned short* __restrict__ qb,
                                              const unsigned short* __restrict__ kb,
                                              const unsigned short* __restrict__ vb,
                                              const float* __restrict__ dm,
                                              float* __restrict__ out0) {
  __shared__ __align__(16) unsigned short QsA[4096];
  __shared__ __align__(16) unsigned short KsA[4096];
  __shared__ __align__(16) unsigned short VtA[4096];
  __shared__ __align__(16) unsigned short PsA[4096];
  char* qs = (char*)QsA; char* ks = (char*)KsA;
  char* vt = (char*)VtA; char* ps = (char*)PsA;
  const int bh = blockIdx.x;
  const int qt = blockIdx.y;
  const int t  = threadIdx.x;
  const int w = t >> 6, l = t & 63, r = l & 15, g = l >> 4;
  const size_t hbase = (size_t)bh << 16;
  const char* qg = (const char*)(qb + hbase + ((size_t)qt << 12));
  const char* kg = (const char*)(kb + hbase);
  const char* vg = (const char*)(vb + hbase);
  const float* mp = dm + ((size_t)bh << 20) + ((size_t)(qt * 64) << 10);
  // mask staging: lane t>>2-th row of this wave's 16-row strip, quarter t&3
  const float* mrow_p = mp + (size_t)(w * 16 + ((l >> 2))) * 1024 + (l & 3) * 16;

#pragma unroll
  for (int i = 0; i < 2; i++) {
    int cid = t + (i << 8);
    int row = cid >> 3, slot = cid & 7;
    uint4 val = *(const uint4*)(qg + row * 128 + slot * 16);
    *(uint4*)(qs + SWZ(row, slot * 16)) = val;
  }

  float m_run[4] = {-INFINITY, -INFINITY, -INFINITY, -INFINITY};
  float l_run[4] = {0.0f, 0.0f, 0.0f, 0.0f};
  f32x4 O[4] = {};

  for (int kt = 0; kt < 16; kt++) {
    __syncthreads();
#pragma unroll
    for (int i = 0; i < 2; i++) {
      int cid = t + (i << 8);
      int row = cid >> 3, slot = cid & 7;
      uint4 val = *(const uint4*)(kg + (size_t)(kt * 64 + row) * 128 + slot * 16);
      *(uint4*)(ks + SWZ(row, slot * 16)) = val;
    }
    {
      int j = t & 63, dh = t >> 6;
      const char* vrow = vg + (size_t)(kt * 64 + j) * 128 + dh * 32;
      u16x8 v0 = *(const u16x8*)(vrow);
      u16x8 v1 = *(const u16x8*)(vrow + 16);
#pragma unroll
      for (int e = 0; e < 8; e++) {
        *(unsigned short*)(vt + SWZ(dh * 16 + e, 2 * j))     = v0[e];
        *(unsigned short*)(vt + SWZ(dh * 16 + 8 + e, 2 * j)) = v1[e];
      }
    }
    // ---- mask: 4x float4 contiguous loads + 16-bit pack (per lane: own row-quarter)
    unsigned bits;
    {
      const float* mrp = mrow_p + kt * 64;
      float4 nm0 = *(const float4*)(mrp);
      float4 nm1 = *(const float4*)(mrp + 4);
      float4 nm2 = *(const float4*)(mrp + 8);
      float4 nm3 = *(const float4*)(mrp + 12);
      bits  = (nm0.x < 0.1f) << 0;  bits |= (nm0.y < 0.1f) << 1;
      bits |= (nm0.z < 0.1f) << 2;  bits |= (nm0.w < 0.1f) << 3;
      bits |= (nm1.x < 0.1f) << 4;  bits |= (nm1.y < 0.1f) << 5;
      bits |= (nm1.z < 0.1f) << 6;  bits |= (nm1.w < 0.1f) << 7;
      bits |= (nm2.x < 0.1f) << 8;  bits |= (nm2.y < 0.1f) << 9;
      bits |= (nm2.z < 0.1f) << 10; bits |= (nm2.w < 0.1f) << 11;
      bits |= (nm3.x < 0.1f) << 12; bits |= (nm3.y < 0.1f) << 13;
      bits |= (nm3.z < 0.1f) << 14; bits |= (nm3.w < 0.1f) << 15;
    }
    __syncthreads();

    f32x4 s[4] = {};
    bf16x8 aQ[2];
#pragma unroll
    for (int kc = 0; kc < 2; kc++)
      aQ[kc] = *(const bf16x8*)(qs + SWZ(w * 16 + r, kc * 64 + g * 16));
#pragma unroll
    for (int jt = 0; jt < 4; jt++) {
#pragma unroll
      for (int kc = 0; kc < 2; kc++) {
        bf16x8 bK = *(const bf16x8*)(ks + SWZ(jt * 16 + r, kc * 64 + g * 16));
        s[jt] = __builtin_amdgcn_mfma_f32_16x16x32_bf16(aQ[kc], bK, s[jt], 0, 0, 0);
      }
    }
    // fetch mask quarters from producing lanes: row g*4+reg quarter jt <- lane g*16+reg*4+jt
    float sv[4][4];
#pragma unroll
    for (int jt = 0; jt < 4; jt++)
#pragma unroll
      for (int reg = 0; reg < 4; reg++) {
        const unsigned mb = __shfl((int)bits, (g << 4) + (reg << 2) + jt);
        const float pen = ((mb >> r) & 1) ? -1e12f : 0.0f;
        sv[jt][reg] = fmaf(s[jt][reg], 0.125f, pen);
      }

    float alpha[4];
#pragma unroll
    for (int reg = 0; reg < 4; reg++) {
      float mt = fmaxf(fmaxf(sv[0][reg], sv[1][reg]), fmaxf(sv[2][reg], sv[3][reg]));
      mt = fmaxf(mt, __shfl_xor(mt, 1));
      mt = fmaxf(mt, __shfl_xor(mt, 2));
      mt = fmaxf(mt, __shfl_xor(mt, 4));
      mt = fmaxf(mt, __shfl_xor(mt, 8));
      float mn = fmaxf(m_run[reg], mt);
      alpha[reg] = __expf(m_run[reg] - mn);
      m_run[reg] = mn;
    }
#pragma unroll
    for (int reg = 0; reg < 4; reg++) {
      int row = w * 16 + g * 4 + reg;
      float ps_ = 0.0f;
#pragma unroll
      for (int jt = 0; jt < 4; jt++) {
        float p = __expf(sv[jt][reg] - m_run[reg]);
        ps_ += p;
        *(unsigned short*)(ps + SWZ(row, 2 * (jt * 16 + r))) = f2bf(p);
      }
      ps_ += __shfl_xor(ps_, 1);
      ps_ += __shfl_xor(ps_, 2);
      ps_ += __shfl_xor(ps_, 4);
      ps_ += __shfl_xor(ps_, 8);
      l_run[reg] = l_run[reg] * alpha[reg] + ps_;
    }
#pragma unroll
    for (int dt = 0; dt < 4; dt++)
#pragma unroll
      for (int reg = 0; reg < 4; reg++)
        O[dt][reg] *= alpha[reg];
    asm volatile("s_waitcnt lgkmcnt(0)" ::: "memory");
    __builtin_amdgcn_sched_barrier(0);
#pragma unroll
    for (int kc = 0; kc < 2; kc++) {
      bf16x8 aP = *(const bf16x8*)(ps + SWZ(w * 16 + r, kc * 64 + g * 16));
#pragma unroll
      for (int dt = 0; dt < 4; dt++) {
        bf16x8 bV = *(const bf16x8*)(vt + SWZ(dt * 16 + r, kc * 64 + g * 16));
        O[dt] = __builtin_amdgcn_mfma_f32_16x16x32_bf16(aP, bV, O[dt], 0, 0, 0);
      }
    }
  }
  const int bb = bh / NH, hh = bh % NH;
  float inv[4];
#pragma unroll
  for (int reg = 0; reg < 4; reg++) inv[reg] = 1.0f / l_run[reg];
  float* op = out0 + ((size_t)(bb * 1024 + qt * 64 + w * 16 + g * 4)) * 768 + hh * 64 + r;
#pragma unroll
  for (int reg = 0; reg < 4; reg++)
#pragma unroll
    for (int dt = 0; dt < 4; dt++)
      op[(size_t)reg * 768 + dt * 16] = O[dt][reg] * inv[reg];
}

// ---------------- K3: depthwise 3x3 'SAME' (round-4)
__global__ __launch_bounds__(256) void k_dwconv(const float* __restrict__ y,
                                                const float* __restrict__ w1,
                                                float* __restrict__ y1) {
  const int bc = blockIdx.x;
  const int c = bc & 255;
  const float* yin = y + (size_t)bc * NPIX;
  float* yout = y1 + (size_t)bc * NPIX;
  float w[9];
#pragma unroll
  for (int i = 0; i < 9; i++) w[i] = w1[c * 9 + i];
  const int t = threadIdx.x;
#pragma unroll
  for (int rep = 0; rep < 4; rep++) {
    int px = t + rep * 256;
    int yy = px >> 5, xx = px & 31;
    float acc = 0.0f;
#pragma unroll
    for (int dy = -1; dy <= 1; dy++) {
      int sy = yy + dy;
      if (sy < 0 || sy > 31) continue;
#pragma unroll
      for (int dx = -1; dx <= 1; dx++) {
        int sx = xx + dx;
        if (sx < 0 || sx > 31) continue;
        acc = fmaf(yin[(sy << 5) + sx], w[(dy + 1) * 3 + dx + 1], acc);
      }
    }
    yout[px] = acc;
  }
}

// ---------------- K3b: y1 [b][c][p] f32 -> y1t [b][p][c] bf16 (round-4)
__global__ __launch_bounds__(256) void k_trans(const float* __restrict__ y1,
                                               unsigned short* __restrict__ y1t) {
  __shared__ float T[64][65];
  const int p0 = blockIdx.x * 64, c0 = blockIdx.y * 64, b = blockIdx.z;
  const int t = threadIdx.x;
  const float* src = y1 + ((size_t)b << 18);
  {
    const int pl = t & 63, cl0 = t >> 6;
#pragma unroll
    for (int i = 0; i < 16; i++) {
      int cl = cl0 * 16 + i;
      T[cl][pl] = src[(size_t)(c0 + cl) * 1024 + p0 + pl];
    }
  }
  __syncthreads();
  {
    const int cl = t & 63, pl0 = t >> 6;
    unsigned short* dst = y1t + ((size_t)b << 18);
#pragma unroll
    for (int i = 0; i < 16; i++) {
      int pl = pl0 * 16 + i;
      dst[(size_t)(p0 + pl) * 256 + c0 + cl] = f2bf(T[cl][pl]);
    }
  }
}

// ---------------- K4: 1x1 conv bf16 MFMA (round-4); fused BN partials
__global__ __launch_bounds__(256) void k_c1x1(const unsigned short* __restrict__ W2b,
                                              const unsigned short* __restrict__ y1t,
                                              float* __restrict__ Y2,
                                              float* __restrict__ bn_sum,
                                              float* __restrict__ bn_sumsq) {
  __shared__ __align__(16) char AsB[16384];
  __shared__ __align__(16) char BsB[16384];
  const int t = threadIdx.x;
  const int w = t >> 6, l = t & 63;
  const int r = l & 15, g = l >> 4;
  const int wr = w >> 1, wc = w & 1;
  const int m0 = blockIdx.y * 128;
  const int n0 = blockIdx.x * 128;
  const int b  = blockIdx.z;
  const unsigned short* Bb = y1t + ((size_t)b << 18);
  const int rsel  = l >> 3;
  const int slotp = (l & 7) ^ (rsel & 7);
  f32x4 acc[4][4] = {};

  for (int step = 0; step < 4; ++step) {
    const int k0 = step * 64;
#pragma unroll
    for (int i = 0; i < 4; i++) {
      const int chunk = (i << 2) + w;
      const int row = (chunk << 3) + rsel;
      GLOAD16(W2b + (size_t)(m0 + row) * 256 + k0 + (slotp << 3),
              AsB + (chunk << 10) + (l << 4));
      GLOAD16(Bb + (size_t)(n0 + row) * 256 + k0 + (slotp << 3),
              BsB + (chunk << 10) + (l << 4));
    }
    __syncthreads();
#pragma unroll
    for (int kk = 0; kk < 2; kk++) {
      bf16x8 a[4], bfr[4];
#pragma unroll
      for (int m = 0; m < 4; m++) {
        const int row = wr * 64 + m * 16 + r;
        a[m] = *(const bf16x8*)(AsB + SWZ(row, kk * 64 + (g << 4)));
      }
#pragma unroll
      for (int n = 0; n < 4; n++) {
        const int row = wc * 64 + n * 16 + r;
        bfr[n] = *(const bf16x8*)(BsB + SWZ(row, kk * 64 + (g << 4)));
      }
#pragma unroll
      for (int m = 0; m < 4; m++)
#pragma unroll
        for (int n = 0; n < 4; n++)
          acc[m][n] = __builtin_amdgcn_mfma_f32_16x16x32_bf16(a[m], bfr[n], acc[m][n], 0, 0, 0);
    }
    __syncthreads();
  }

  float* Yb = Y2 + (((size_t)b * DMODEL) << 10);
#pragma unroll
  for (int m = 0; m < 4; m++) {
#pragma unroll
    for (int reg = 0; reg < 4; reg++) {
      const int oc = m0 + wr * 64 + m * 16 + g * 4 + reg;
      float s = 0.0f, sq = 0.0f;
#pragma unroll
      for (int n = 0; n < 4; n++) {
        const int p = n0 + wc * 64 + n * 16 + r;
        const float val = acc[m][n][reg];
        Yb[((size_t)oc << 10) + p] = val;
        s += val;
        sq = fmaf(val, val, sq);
      }
      s  += __shfl_xor(s, 1);  sq += __shfl_xor(sq, 1);
      s  += __shfl_xor(s, 2);  sq += __shfl_xor(sq, 2);
      s  += __shfl_xor(s, 4);  sq += __shfl_xor(sq, 4);
      s  += __shfl_xor(s, 8);  sq += __shfl_xor(sq, 8);
      if (r == 0) {
        atomicAdd(&bn_sum[oc], s);
        atomicAdd(&bn_sumsq[oc], sq);
      }
    }
  }
}

// ---------------- K6: scale/shift from sums, BN+ReLU -> out1, transpose-add into out0
__global__ __launch_bounds__(256) void k_bnfuse(const float* __restrict__ y2,
                                                const float* __restrict__ bn_sum,
                                                const float* __restrict__ bn_sumsq,
                                                const float* __restrict__ gamma,
                                                const float* __restrict__ beta,
                                                float* __restrict__ out0,
                                                float* __restrict__ out1) {
  __shared__ float T[32][33];
  __shared__ float sc_l[32], sh_l[32];
  const int p0 = blockIdx.x * 32;
  const int c0 = blockIdx.y * 32;
  const int bb = blockIdx.z;
  const int tx = threadIdx.x;
  const int ty = threadIdx.y;
  const int tt = ty * 32 + tx;
  if (tt < 32) {
    const int c = c0 + tt;
    float S = bn_sum[c], SQ = bn_sumsq[c];
    float mean = S * (1.0f / 4096.0f);
    float var = SQ * (1.0f / 4096.0f) - mean * mean;
    float rstd = rsqrtf(var + 1e-5f);
    float s = gamma[c] * rstd;
    sc_l[tt] = s;
    sh_l[tt] = fmaf(-mean, s, beta[c]);
  }
  __syncthreads();
#pragma unroll
  for (int i = 0; i < 4; i++) {
    int cl = ty + 8 * i;
    int c = c0 + cl;
    size_t a = ((size_t)(bb * DMODEL + c) << 10) + p0 + tx;
    float val = fmaxf(fmaf(y2[a], sc_l[cl], sh_l[cl]), 0.0f);
    out1[a] = val;
    T[cl][tx] = val;
  }
  __syncthreads();
#pragma unroll
  for (int i = 0; i < 4; i++) {
    int pl = ty + 8 * i;
    size_t a = ((size_t)((bb << 10) + p0 + pl)) * DMODEL + c0 + tx;
    out0[a] += T[tx][pl];
  }
}

extern "C" void kernel_launch(void* const* d_in, const int* in_sizes, int n_in,
                              void* d_out, int out_size, void* d_ws, size_t ws_size,
                              hipStream_t stream) {
  (void)in_sizes; (void)n_in; (void)out_size; (void)ws_size;
  const float* x    = (const float*)d_in[0];
  const float* y    = (const float*)d_in[1];
  const float* dm   = (const float*)d_in[2];
  const float* wqkv = (const float*)d_in[3];
  const float* w1   = (const float*)d_in[4];
  const float* w2   = (const float*)d_in[5];
  const float* gam  = (const float*)d_in[6];
  const float* bet  = (const float*)d_in[7];
  float* out0 = (float*)d_out;
  float* out1 = out0 + (size_t)B_ * NTOK * DMODEL;

  char* wsb = (char*)d_ws;
  unsigned short* Xb  = (unsigned short*)wsb;
  unsigned short* Wtb = (unsigned short*)(wsb + 6291456);
  unsigned short* W2b = (unsigned short*)(wsb + 9830400);
  unsigned short* qb  = (unsigned short*)(wsb + 10223616);
  unsigned short* kb  = (unsigned short*)(wsb + 16515072);
  unsigned short* vb  = (unsigned short*)(wsb + 22806528);
  unsigned short* y1t = (unsigned short*)(wsb + 29097984);
  float* y2 = (float*)(wsb + 31195136);
  float* y1 = (float*)(wsb + 35389440);
  float* bnacc = (float*)(wsb + 43778048);
  float* bn_sum = bnacc;
  float* bn_sumsq = bnacc + 768;

  k_cvt<<<dim3(3361), 256, 0, stream>>>(x, wqkv, w2, Xb, Wtb, W2b, bnacc);
  k_dwconv<<<dim3(B_ * IMGC), 256, 0, stream>>>(y, w1, y1);
  k_trans<<<dim3(16, 4, B_), 256, 0, stream>>>(y1, y1t);
  k_c1x1<<<dim3(8, 6, B_), 256, 0, stream>>>(W2b, y1t, y2, bn_sum, bn_sumsq);
  k_qkv_gemm<<<dim3(18, 32), 256, 0, stream>>>(Xb, Wtb, qb, kb, vb);
  k_attn<<<dim3(48, 16), 256, 0, stream>>>(qb, kb, vb, dm, out0);
  k_bnfuse<<<dim3(32, 24, B_), dim3(32, 8), 0, stream>>>(y2, bn_sum, bn_sumsq, gam, bet, out0, out1);
}

// Round 10
// 127.970 us; speedup vs baseline: 1.1773x; 1.0931x over previous
//
#include <hip/hip_runtime.h>
#include <cstddef>

#define B_     4
#define NTOK   1024
#define DMODEL 768
#define NH     12
#define IMGC   256
#define NPIX   1024

typedef __attribute__((ext_vector_type(8))) short bf16x8;
typedef __attribute__((ext_vector_type(4))) float f32x4;
typedef __attribute__((ext_vector_type(8))) unsigned short u16x8;

static __device__ __forceinline__ unsigned short f2bf(float f) {
  unsigned int u = __float_as_uint(f);
  u += 0x7FFFu + ((u >> 16) & 1u);
  return (unsigned short)(u >> 16);
}

// swizzled LDS byte address: 128B rows, XOR bits 4..6 with row&7
#define SWZ(row, b) (((row) << 7) + ((b) ^ (((row) & 7) << 4)))

#define GLOAD16(g, l) __builtin_amdgcn_global_load_lds(                      \
    (const __attribute__((address_space(1))) void*)(g),                      \
    (__attribute__((address_space(3))) void*)(l), 16, 0, 0)

// ---------------- K0: merged converts + BN zeroing + depthwise conv planes
// [0,1536): X->Xb ; [1536,3264): Wqkv^T->Wtb ; [3264,3360): W2->W2b ;
// 3360: zero bn accumulators ; [3361,4385): dwconv plane (b*256+c), unchanged code
__global__ __launch_bounds__(256) void k_cvt(const float* __restrict__ X,
                                             const float* __restrict__ Wqkv,
                                             const float* __restrict__ W2,
                                             const float* __restrict__ Yimg,
                                             const float* __restrict__ w1,
                                             unsigned short* __restrict__ Xb,
                                             unsigned short* __restrict__ Wtb,
                                             unsigned short* __restrict__ W2b,
                                             float* __restrict__ y1,
                                             float* __restrict__ bnacc) {
  __shared__ unsigned short T[32][33];
  const int bid = blockIdx.x;
  const int t = threadIdx.x;
  if (bid < 1536) {
    const size_t i8 = (size_t)bid * 256 + t;
    const float4 a = *(const float4*)(X + i8 * 8);
    const float4 b = *(const float4*)(X + i8 * 8 + 4);
    u16x8 o;
    o[0] = f2bf(a.x); o[1] = f2bf(a.y); o[2] = f2bf(a.z); o[3] = f2bf(a.w);
    o[4] = f2bf(b.x); o[5] = f2bf(b.y); o[6] = f2bf(b.z); o[7] = f2bf(b.w);
    *(u16x8*)(Xb + i8 * 8) = o;
  } else if (bid < 3264) {
    const int b2 = bid - 1536;
    const int n0 = (b2 % 72) * 32, k0 = (b2 / 72) * 32;
    const int tx = t & 31, ty = t >> 5;
#pragma unroll
    for (int i = 0; i < 4; i++) {
      int kl = ty + i * 8;
      T[tx][kl] = f2bf(Wqkv[(size_t)(k0 + kl) * 2304 + n0 + tx]);
    }
    __syncthreads();
#pragma unroll
    for (int i = 0; i < 4; i++) {
      int nl = ty + i * 8;
      Wtb[(size_t)(n0 + nl) * 768 + k0 + tx] = T[nl][tx];
    }
  } else if (bid < 3360) {
    const size_t i8 = (size_t)(bid - 3264) * 256 + t;
    const float4 a = *(const float4*)(W2 + i8 * 8);
    const float4 b = *(const float4*)(W2 + i8 * 8 + 4);
    u16x8 o;
    o[0] = f2bf(a.x); o[1] = f2bf(a.y); o[2] = f2bf(a.z); o[3] = f2bf(a.w);
    o[4] = f2bf(b.x); o[5] = f2bf(b.y); o[6] = f2bf(b.z); o[7] = f2bf(b.w);
    *(u16x8*)(W2b + i8 * 8) = o;
  } else if (bid == 3360) {
    for (int i = t; i < 1536; i += 256) bnacc[i] = 0.0f;
  } else {
    // depthwise 3x3 'SAME', one (b,c) plane per block — identical to old k_dwconv
    const int bc = bid - 3361;
    const int c = bc & 255;
    const float* yin = Yimg + (size_t)bc * NPIX;
    float* yout = y1 + (size_t)bc * NPIX;
    float w[9];
#pragma unroll
    for (int i = 0; i < 9; i++) w[i] = w1[c * 9 + i];
#pragma unroll
    for (int rep = 0; rep < 4; rep++) {
      int px = t + rep * 256;
      int yy = px >> 5, xx = px & 31;
      float acc = 0.0f;
#pragma unroll
      for (int dy = -1; dy <= 1; dy++) {
        int sy = yy + dy;
        if (sy < 0 || sy > 31) continue;
#pragma unroll
        for (int dx = -1; dx <= 1; dx++) {
          int sx = xx + dx;
          if (sx < 0 || sx > 31) continue;
          acc = fmaf(yin[(sy << 5) + sx], w[(dy + 1) * 3 + dx + 1], acc);
        }
      }
      yout[px] = acc;
    }
  }
}

// ---------------- K1: QKV GEMM bf16 MFMA (round-4 single-buffer)
__global__ __launch_bounds__(256) void k_qkv_gemm(const unsigned short* __restrict__ Xb,
                                                  const unsigned short* __restrict__ Wt,
                                                  unsigned short* __restrict__ q,
                                                  unsigned short* __restrict__ k,
                                                  unsigned short* __restrict__ v) {
  __shared__ __align__(16) char AsB[16384];
  __shared__ __align__(16) char BsB[16384];
  const int t = threadIdx.x;
  const int w = t >> 6, l = t & 63;
  const int r = l & 15, g = l >> 4;
  const int wr = w >> 1, wc = w & 1;
  const int m0 = blockIdx.y * 128;
  const int n0 = blockIdx.x * 128;
  const int rsel  = l >> 3;
  const int slotp = (l & 7) ^ (rsel & 7);
  f32x4 acc[4][4] = {};

  for (int step = 0; step < 12; ++step) {
    const int k0 = step * 64;
#pragma unroll
    for (int i = 0; i < 4; i++) {
      const int chunk = (i << 2) + w;
      const int row = (chunk << 3) + rsel;
      GLOAD16(Xb + (size_t)(m0 + row) * 768 + k0 + (slotp << 3),
              AsB + (chunk << 10) + (l << 4));
      GLOAD16(Wt + (size_t)(n0 + row) * 768 + k0 + (slotp << 3),
              BsB + (chunk << 10) + (l << 4));
    }
    __syncthreads();
#pragma unroll
    for (int kk = 0; kk < 2; kk++) {
      bf16x8 a[4], b[4];
#pragma unroll
      for (int m = 0; m < 4; m++) {
        const int row = wr * 64 + m * 16 + r;
        a[m] = *(const bf16x8*)(AsB + SWZ(row, kk * 64 + (g << 4)));
      }
#pragma unroll
      for (int n = 0; n < 4; n++) {
        const int row = wc * 64 + n * 16 + r;
        b[n] = *(const bf16x8*)(BsB + SWZ(row, kk * 64 + (g << 4)));
      }
#pragma unroll
      for (int m = 0; m < 4; m++)
#pragma unroll
        for (int n = 0; n < 4; n++)
          acc[m][n] = __builtin_amdgcn_mfma_f32_16x16x32_bf16(a[m], b[n], acc[m][n], 0, 0, 0);
    }
    __syncthreads();
  }

  const int which = blockIdx.x / 6;
  const int cbase = (blockIdx.x - which * 6) * 128 + wc * 64;
  unsigned short* dst = which == 0 ? q : (which == 1 ? k : v);
#pragma unroll
  for (int m = 0; m < 4; m++) {
    const int grow = m0 + wr * 64 + m * 16 + g * 4;
#pragma unroll
    for (int n = 0; n < 4; n++) {
      const int c = cbase + n * 16 + r;
      const int head = c >> 6, dim = c & 63;
#pragma unroll
      for (int reg = 0; reg < 4; reg++) {
        const int row = grow + reg;
        const int bb = row >> 10, tok = row & 1023;
        dst[((size_t)(((bb * NH + head) << 10) + tok) << 6) + dim] = f2bf(acc[m][n][reg]);
      }
    }
  }
}

// ---------------- K2: flash attention (round-4 structure; epilogue fuses BN+ReLU y_tok add)
__global__ __launch_bounds__(256) void k_attn(const unsigned short* __restrict__ qb,
                                              const unsigned short* __restrict__ kb,
                                              const unsigned short* __restrict__ vb,
                                              const float* __restrict__ dm,
                                              const float* __restrict__ y2,
                                              const float* __restrict__ bn_sum,
                                              const float* __restrict__ bn_sumsq,
                                              const float* __restrict__ gamma,
                                              const float* __restrict__ beta,
                                              float* __restrict__ out0) {
  __shared__ __align__(16) unsigned short QsA[4096];
  __shared__ __align__(16) unsigned short KsA[4096];
  __shared__ __align__(16) unsigned short VtA[4096];
  __shared__ __align__(16) unsigned short PsA[4096];
  char* qs = (char*)QsA; char* ks = (char*)KsA;
  char* vt = (char*)VtA; char* ps = (char*)PsA;
  const int bh = blockIdx.x;
  const int qt = blockIdx.y;
  const int t  = threadIdx.x;
  const int w = t >> 6, l = t & 63, r = l & 15, g = l >> 4;
  const size_t hbase = (size_t)bh << 16;
  const char* qg = (const char*)(qb + hbase + ((size_t)qt << 12));
  const char* kg = (const char*)(kb + hbase);
  const char* vg = (const char*)(vb + hbase);
  const float* mp = dm + ((size_t)bh << 20) + ((size_t)(qt * 64) << 10);

#pragma unroll
  for (int i = 0; i < 2; i++) {
    int cid = t + (i << 8);
    int row = cid >> 3, slot = cid & 7;
    uint4 val = *(const uint4*)(qg + row * 128 + slot * 16);
    *(uint4*)(qs + SWZ(row, slot * 16)) = val;
  }

  float m_run[4] = {-INFINITY, -INFINITY, -INFINITY, -INFINITY};
  float l_run[4] = {0.0f, 0.0f, 0.0f, 0.0f};
  f32x4 O[4] = {};

  for (int kt = 0; kt < 16; kt++) {
    __syncthreads();
#pragma unroll
    for (int i = 0; i < 2; i++) {
      int cid = t + (i << 8);
      int row = cid >> 3, slot = cid & 7;
      uint4 val = *(const uint4*)(kg + (size_t)(kt * 64 + row) * 128 + slot * 16);
      *(uint4*)(ks + SWZ(row, slot * 16)) = val;
    }
    {
      int j = t & 63, dh = t >> 6;
      const char* vrow = vg + (size_t)(kt * 64 + j) * 128 + dh * 32;
      u16x8 v0 = *(const u16x8*)(vrow);
      u16x8 v1 = *(const u16x8*)(vrow + 16);
#pragma unroll
      for (int e = 0; e < 8; e++) {
        *(unsigned short*)(vt + SWZ(dh * 16 + e, 2 * j))     = v0[e];
        *(unsigned short*)(vt + SWZ(dh * 16 + 8 + e, 2 * j)) = v1[e];
      }
    }
    float md[4][4];
    {
      const float* mr = mp + (size_t)(w * 16 + g * 4) * 1024 + kt * 64 + r;
#pragma unroll
      for (int reg = 0; reg < 4; reg++)
#pragma unroll
        for (int jt = 0; jt < 4; jt++)
          md[reg][jt] = mr[reg * 1024 + jt * 16];
    }
    __syncthreads();

    f32x4 s[4] = {};
    bf16x8 aQ[2];
#pragma unroll
    for (int kc = 0; kc < 2; kc++)
      aQ[kc] = *(const bf16x8*)(qs + SWZ(w * 16 + r, kc * 64 + g * 16));
#pragma unroll
    for (int jt = 0; jt < 4; jt++) {
#pragma unroll
      for (int kc = 0; kc < 2; kc++) {
        bf16x8 bK = *(const bf16x8*)(ks + SWZ(jt * 16 + r, kc * 64 + g * 16));
        s[jt] = __builtin_amdgcn_mfma_f32_16x16x32_bf16(aQ[kc], bK, s[jt], 0, 0, 0);
      }
    }
    float sv[4][4];
#pragma unroll
    for (int jt = 0; jt < 4; jt++)
#pragma unroll
      for (int reg = 0; reg < 4; reg++)
        sv[jt][reg] = s[jt][reg] * 0.125f + (md[reg][jt] < 0.1f ? -1e12f : 0.0f);

    float alpha[4];
#pragma unroll
    for (int reg = 0; reg < 4; reg++) {
      float mt = fmaxf(fmaxf(sv[0][reg], sv[1][reg]), fmaxf(sv[2][reg], sv[3][reg]));
      mt = fmaxf(mt, __shfl_xor(mt, 1));
      mt = fmaxf(mt, __shfl_xor(mt, 2));
      mt = fmaxf(mt, __shfl_xor(mt, 4));
      mt = fmaxf(mt, __shfl_xor(mt, 8));
      float mn = fmaxf(m_run[reg], mt);
      alpha[reg] = __expf(m_run[reg] - mn);
      m_run[reg] = mn;
    }
#pragma unroll
    for (int reg = 0; reg < 4; reg++) {
      int row = w * 16 + g * 4 + reg;
      float ps_ = 0.0f;
#pragma unroll
      for (int jt = 0; jt < 4; jt++) {
        float p = __expf(sv[jt][reg] - m_run[reg]);
        ps_ += p;
        *(unsigned short*)(ps + SWZ(row, 2 * (jt * 16 + r))) = f2bf(p);
      }
      ps_ += __shfl_xor(ps_, 1);
      ps_ += __shfl_xor(ps_, 2);
      ps_ += __shfl_xor(ps_, 4);
      ps_ += __shfl_xor(ps_, 8);
      l_run[reg] = l_run[reg] * alpha[reg] + ps_;
    }
#pragma unroll
    for (int dt = 0; dt < 4; dt++)
#pragma unroll
      for (int reg = 0; reg < 4; reg++)
        O[dt][reg] *= alpha[reg];
    asm volatile("s_waitcnt lgkmcnt(0)" ::: "memory");
    __builtin_amdgcn_sched_barrier(0);
#pragma unroll
    for (int kc = 0; kc < 2; kc++) {
      bf16x8 aP = *(const bf16x8*)(ps + SWZ(w * 16 + r, kc * 64 + g * 16));
#pragma unroll
      for (int dt = 0; dt < 4; dt++) {
        bf16x8 bV = *(const bf16x8*)(vt + SWZ(dt * 16 + r, kc * 64 + g * 16));
        O[dt] = __builtin_amdgcn_mfma_f32_16x16x32_bf16(aP, bV, O[dt], 0, 0, 0);
      }
    }
  }
  // ---- epilogue: out0 = attn_out + relu(bn(y2^T)) for this exact tile
  const int bb = bh / NH, hh = bh % NH;
  float inv[4];
#pragma unroll
  for (int reg = 0; reg < 4; reg++) inv[reg] = 1.0f / l_run[reg];
  // BN scale/shift for the 4 channels this lane touches: c = hh*64 + dt*16 + r
  float scv[4], shv[4];
#pragma unroll
  for (int dt = 0; dt < 4; dt++) {
    const int c = hh * 64 + dt * 16 + r;
    const float S = bn_sum[c], SQ = bn_sumsq[c];
    const float mean = S * (1.0f / 4096.0f);
    const float var = SQ * (1.0f / 4096.0f) - mean * mean;
    const float rstd = rsqrtf(var + 1e-5f);
    const float sc = gamma[c] * rstd;
    scv[dt] = sc;
    shv[dt] = fmaf(-mean, sc, beta[c]);
  }
  const int prow = qt * 64 + w * 16 + g * 4;   // token row for reg=0 (mult of 4)
  const float* y2p = y2 + (((size_t)(bb * DMODEL + hh * 64 + r)) << 10) + prow;
  float4 yq[4];
#pragma unroll
  for (int dt = 0; dt < 4; dt++)
    yq[dt] = *(const float4*)(y2p + ((size_t)dt << 14));  // dt*16 channels * 1024
  float* op = out0 + ((size_t)(bb * 1024 + prow)) * 768 + hh * 64 + r;
#pragma unroll
  for (int reg = 0; reg < 4; reg++)
#pragma unroll
    for (int dt = 0; dt < 4; dt++) {
      const float yv = (&yq[dt].x)[reg];
      const float ytok = fmaxf(fmaf(yv, scv[dt], shv[dt]), 0.0f);
      op[(size_t)reg * 768 + dt * 16] = fmaf(O[dt][reg], inv[reg], ytok);
    }
}

// ---------------- K3b: y1 [b][c][p] f32 -> y1t [b][p][c] bf16 (round-4)
__global__ __launch_bounds__(256) void k_trans(const float* __restrict__ y1,
                                               unsigned short* __restrict__ y1t) {
  __shared__ float T[64][65];
  const int p0 = blockIdx.x * 64, c0 = blockIdx.y * 64, b = blockIdx.z;
  const int t = threadIdx.x;
  const float* src = y1 + ((size_t)b << 18);
  {
    const int pl = t & 63, cl0 = t >> 6;
#pragma unroll
    for (int i = 0; i < 16; i++) {
      int cl = cl0 * 16 + i;
      T[cl][pl] = src[(size_t)(c0 + cl) * 1024 + p0 + pl];
    }
  }
  __syncthreads();
  {
    const int cl = t & 63, pl0 = t >> 6;
    unsigned short* dst = y1t + ((size_t)b << 18);
#pragma unroll
    for (int i = 0; i < 16; i++) {
      int pl = pl0 * 16 + i;
      dst[(size_t)(p0 + pl) * 256 + c0 + cl] = f2bf(T[cl][pl]);
    }
  }
}

// ---------------- K4: 1x1 conv bf16 MFMA (round-4); fused BN partials
__global__ __launch_bounds__(256) void k_c1x1(const unsigned short* __restrict__ W2b,
                                              const unsigned short* __restrict__ y1t,
                                              float* __restrict__ Y2,
                                              float* __restrict__ bn_sum,
                                              float* __restrict__ bn_sumsq) {
  __shared__ __align__(16) char AsB[16384];
  __shared__ __align__(16) char BsB[16384];
  const int t = threadIdx.x;
  const int w = t >> 6, l = t & 63;
  const int r = l & 15, g = l >> 4;
  const int wr = w >> 1, wc = w & 1;
  const int m0 = blockIdx.y * 128;
  const int n0 = blockIdx.x * 128;
  const int b  = blockIdx.z;
  const unsigned short* Bb = y1t + ((size_t)b << 18);
  const int rsel  = l >> 3;
  const int slotp = (l & 7) ^ (rsel & 7);
  f32x4 acc[4][4] = {};

  for (int step = 0; step < 4; ++step) {
    const int k0 = step * 64;
#pragma unroll
    for (int i = 0; i < 4; i++) {
      const int chunk = (i << 2) + w;
      const int row = (chunk << 3) + rsel;
      GLOAD16(W2b + (size_t)(m0 + row) * 256 + k0 + (slotp << 3),
              AsB + (chunk << 10) + (l << 4));
      GLOAD16(Bb + (size_t)(n0 + row) * 256 + k0 + (slotp << 3),
              BsB + (chunk << 10) + (l << 4));
    }
    __syncthreads();
#pragma unroll
    for (int kk = 0; kk < 2; kk++) {
      bf16x8 a[4], bfr[4];
#pragma unroll
      for (int m = 0; m < 4; m++) {
        const int row = wr * 64 + m * 16 + r;
        a[m] = *(const bf16x8*)(AsB + SWZ(row, kk * 64 + (g << 4)));
      }
#pragma unroll
      for (int n = 0; n < 4; n++) {
        const int row = wc * 64 + n * 16 + r;
        bfr[n] = *(const bf16x8*)(BsB + SWZ(row, kk * 64 + (g << 4)));
      }
#pragma unroll
      for (int m = 0; m < 4; m++)
#pragma unroll
        for (int n = 0; n < 4; n++)
          acc[m][n] = __builtin_amdgcn_mfma_f32_16x16x32_bf16(a[m], bfr[n], acc[m][n], 0, 0, 0);
    }
    __syncthreads();
  }

  float* Yb = Y2 + (((size_t)b * DMODEL) << 10);
#pragma unroll
  for (int m = 0; m < 4; m++) {
#pragma unroll
    for (int reg = 0; reg < 4; reg++) {
      const int oc = m0 + wr * 64 + m * 16 + g * 4 + reg;
      float s = 0.0f, sq = 0.0f;
#pragma unroll
      for (int n = 0; n < 4; n++) {
        const int p = n0 + wc * 64 + n * 16 + r;
        const float val = acc[m][n][reg];
        Yb[((size_t)oc << 10) + p] = val;
        s += val;
        sq = fmaf(val, val, sq);
      }
      s  += __shfl_xor(s, 1);  sq += __shfl_xor(sq, 1);
      s  += __shfl_xor(s, 2);  sq += __shfl_xor(sq, 2);
      s  += __shfl_xor(s, 4);  sq += __shfl_xor(sq, 4);
      s  += __shfl_xor(s, 8);  sq += __shfl_xor(sq, 8);
      if (r == 0) {
        atomicAdd(&bn_sum[oc], s);
        atomicAdd(&bn_sumsq[oc], sq);
      }
    }
  }
}

// ---------------- K6: out1 only — BN+ReLU elementwise, one (b,c) row per block
__global__ __launch_bounds__(256) void k_bnout1(const float* __restrict__ y2,
                                                const float* __restrict__ bn_sum,
                                                const float* __restrict__ bn_sumsq,
                                                const float* __restrict__ gamma,
                                                const float* __restrict__ beta,
                                                float* __restrict__ out1) {
  const int row = blockIdx.x;           // b*768 + c
  const int c = row % DMODEL;
  const int t = threadIdx.x;
  const float S = bn_sum[c], SQ = bn_sumsq[c];
  const float mean = S * (1.0f / 4096.0f);
  const float var = SQ * (1.0f / 4096.0f) - mean * mean;
  const float rstd = rsqrtf(var + 1e-5f);
  const float sc = gamma[c] * rstd;
  const float sh = fmaf(-mean, sc, beta[c]);
  const float* src = y2 + ((size_t)row << 10) + t * 4;
  float* dst = out1 + ((size_t)row << 10) + t * 4;
  float4 v = *(const float4*)src;
  v.x = fmaxf(fmaf(v.x, sc, sh), 0.0f);
  v.y = fmaxf(fmaf(v.y, sc, sh), 0.0f);
  v.z = fmaxf(fmaf(v.z, sc, sh), 0.0f);
  v.w = fmaxf(fmaf(v.w, sc, sh), 0.0f);
  *(float4*)dst = v;
}

extern "C" void kernel_launch(void* const* d_in, const int* in_sizes, int n_in,
                              void* d_out, int out_size, void* d_ws, size_t ws_size,
                              hipStream_t stream) {
  (void)in_sizes; (void)n_in; (void)out_size; (void)ws_size;
  const float* x    = (const float*)d_in[0];
  const float* y    = (const float*)d_in[1];
  const float* dm   = (const float*)d_in[2];
  const float* wqkv = (const float*)d_in[3];
  const float* w1   = (const float*)d_in[4];
  const float* w2   = (const float*)d_in[5];
  const float* gam  = (const float*)d_in[6];
  const float* bet  = (const float*)d_in[7];
  float* out0 = (float*)d_out;
  float* out1 = out0 + (size_t)B_ * NTOK * DMODEL;

  char* wsb = (char*)d_ws;
  unsigned short* Xb  = (unsigned short*)wsb;
  unsigned short* Wtb = (unsigned short*)(wsb + 6291456);
  unsigned short* W2b = (unsigned short*)(wsb + 9830400);
  unsigned short* qb  = (unsigned short*)(wsb + 10223616);
  unsigned short* kb  = (unsigned short*)(wsb + 16515072);
  unsigned short* vb  = (unsigned short*)(wsb + 22806528);
  unsigned short* y1t = (unsigned short*)(wsb + 29097984);
  float* y2 = (float*)(wsb + 31195136);
  float* y1 = (float*)(wsb + 35389440);
  float* bnacc = (float*)(wsb + 43778048);
  float* bn_sum = bnacc;
  float* bn_sumsq = bnacc + 768;

  k_cvt<<<dim3(4385), 256, 0, stream>>>(x, wqkv, w2, y, w1, Xb, Wtb, W2b, y1, bnacc);
  k_trans<<<dim3(16, 4, B_), 256, 0, stream>>>(y1, y1t);
  k_c1x1<<<dim3(8, 6, B_), 256, 0, stream>>>(W2b, y1t, y2, bn_sum, bn_sumsq);
  k_qkv_gemm<<<dim3(18, 32), 256, 0, stream>>>(Xb, Wtb, qb, kb, vb);
  k_attn<<<dim3(48, 16), 256, 0, stream>>>(qb, kb, vb, dm, y2, bn_sum, bn_sumsq, gam, bet, out0);
  k_bnout1<<<dim3(B_ * DMODEL), 256, 0, stream>>>(y2, bn_sum, bn_sumsq, gam, bet, out1);
}

// Round 11
// 121.738 us; speedup vs baseline: 1.2376x; 1.0512x over previous
//
#include <hip/hip_runtime.h>
#include <cstddef>

#define B_     4
#define NTOK   1024
#define DMODEL 768
#define NH     12
#define IMGC   256
#define NPIX   1024

typedef __attribute__((ext_vector_type(8))) short bf16x8;
typedef __attribute__((ext_vector_type(4))) float f32x4;
typedef __attribute__((ext_vector_type(8))) unsigned short u16x8;

static __device__ __forceinline__ unsigned short f2bf(float f) {
  unsigned int u = __float_as_uint(f);
  u += 0x7FFFu + ((u >> 16) & 1u);
  return (unsigned short)(u >> 16);
}

// swizzled LDS byte address: 128B rows, XOR bits 4..6 with row&7
#define SWZ(row, b) (((row) << 7) + ((b) ^ (((row) & 7) << 4)))

#define GLOAD16(g, l) __builtin_amdgcn_global_load_lds(                      \
    (const __attribute__((address_space(1))) void*)(g),                      \
    (__attribute__((address_space(3))) void*)(l), 16, 0, 0)

// ---------------- K0: merged converts + BN zeroing + depthwise conv planes
// [0,1536): X->Xb ; [1536,3264): Wqkv^T->Wtb ; [3264,3360): W2->W2b ;
// 3360: zero bn accumulators ; [3361,4385): dwconv plane (b*256+c)
__global__ __launch_bounds__(256) void k_cvt(const float* __restrict__ X,
                                             const float* __restrict__ Wqkv,
                                             const float* __restrict__ W2,
                                             const float* __restrict__ Yimg,
                                             const float* __restrict__ w1,
                                             unsigned short* __restrict__ Xb,
                                             unsigned short* __restrict__ Wtb,
                                             unsigned short* __restrict__ W2b,
                                             float* __restrict__ y1,
                                             float* __restrict__ bnacc) {
  __shared__ unsigned short T[32][33];
  const int bid = blockIdx.x;
  const int t = threadIdx.x;
  if (bid < 1536) {
    const size_t i8 = (size_t)bid * 256 + t;
    const float4 a = *(const float4*)(X + i8 * 8);
    const float4 b = *(const float4*)(X + i8 * 8 + 4);
    u16x8 o;
    o[0] = f2bf(a.x); o[1] = f2bf(a.y); o[2] = f2bf(a.z); o[3] = f2bf(a.w);
    o[4] = f2bf(b.x); o[5] = f2bf(b.y); o[6] = f2bf(b.z); o[7] = f2bf(b.w);
    *(u16x8*)(Xb + i8 * 8) = o;
  } else if (bid < 3264) {
    const int b2 = bid - 1536;
    const int n0 = (b2 % 72) * 32, k0 = (b2 / 72) * 32;
    const int tx = t & 31, ty = t >> 5;
#pragma unroll
    for (int i = 0; i < 4; i++) {
      int kl = ty + i * 8;
      T[tx][kl] = f2bf(Wqkv[(size_t)(k0 + kl) * 2304 + n0 + tx]);
    }
    __syncthreads();
#pragma unroll
    for (int i = 0; i < 4; i++) {
      int nl = ty + i * 8;
      Wtb[(size_t)(n0 + nl) * 768 + k0 + tx] = T[nl][tx];
    }
  } else if (bid < 3360) {
    const size_t i8 = (size_t)(bid - 3264) * 256 + t;
    const float4 a = *(const float4*)(W2 + i8 * 8);
    const float4 b = *(const float4*)(W2 + i8 * 8 + 4);
    u16x8 o;
    o[0] = f2bf(a.x); o[1] = f2bf(a.y); o[2] = f2bf(a.z); o[3] = f2bf(a.w);
    o[4] = f2bf(b.x); o[5] = f2bf(b.y); o[6] = f2bf(b.z); o[7] = f2bf(b.w);
    *(u16x8*)(W2b + i8 * 8) = o;
  } else if (bid == 3360) {
    for (int i = t; i < 1536; i += 256) bnacc[i] = 0.0f;
  } else {
    const int bc = bid - 3361;
    const int c = bc & 255;
    const float* yin = Yimg + (size_t)bc * NPIX;
    float* yout = y1 + (size_t)bc * NPIX;
    float w[9];
#pragma unroll
    for (int i = 0; i < 9; i++) w[i] = w1[c * 9 + i];
#pragma unroll
    for (int rep = 0; rep < 4; rep++) {
      int px = t + rep * 256;
      int yy = px >> 5, xx = px & 31;
      float acc = 0.0f;
#pragma unroll
      for (int dy = -1; dy <= 1; dy++) {
        int sy = yy + dy;
        if (sy < 0 || sy > 31) continue;
#pragma unroll
        for (int dx = -1; dx <= 1; dx++) {
          int sx = xx + dx;
          if (sx < 0 || sx > 31) continue;
          acc = fmaf(yin[(sy << 5) + sx], w[(dy + 1) * 3 + dx + 1], acc);
        }
      }
      yout[px] = acc;
    }
  }
}

// ---------------- K3b: y1 [b][c][p] f32 -> y1t [b][p][c] bf16
__global__ __launch_bounds__(256) void k_trans(const float* __restrict__ y1,
                                               unsigned short* __restrict__ y1t) {
  __shared__ float T[64][65];
  const int p0 = blockIdx.x * 64, c0 = blockIdx.y * 64, b = blockIdx.z;
  const int t = threadIdx.x;
  const float* src = y1 + ((size_t)b << 18);
  {
    const int pl = t & 63, cl0 = t >> 6;
#pragma unroll
    for (int i = 0; i < 16; i++) {
      int cl = cl0 * 16 + i;
      T[cl][pl] = src[(size_t)(c0 + cl) * 1024 + p0 + pl];
    }
  }
  __syncthreads();
  {
    const int cl = t & 63, pl0 = t >> 6;
    unsigned short* dst = y1t + ((size_t)b << 18);
#pragma unroll
    for (int i = 0; i < 16; i++) {
      int pl = pl0 * 16 + i;
      dst[(size_t)(p0 + pl) * 256 + c0 + cl] = f2bf(T[cl][pl]);
    }
  }
}

// ---------------- K1: merged MFMA GEMMs.
// blocks [0,576): QKV GEMM (18x32 tiles) ; [576,768): 1x1 conv (8x6x4) + BN partials
__global__ __launch_bounds__(256) void k_mm(const unsigned short* __restrict__ Xb,
                                            const unsigned short* __restrict__ Wt,
                                            unsigned short* __restrict__ q,
                                            unsigned short* __restrict__ k,
                                            unsigned short* __restrict__ v,
                                            const unsigned short* __restrict__ W2b,
                                            const unsigned short* __restrict__ y1t,
                                            float* __restrict__ Y2,
                                            float* __restrict__ bn_sum,
                                            float* __restrict__ bn_sumsq) {
  __shared__ __align__(16) char AsB[16384];
  __shared__ __align__(16) char BsB[16384];
  const int bid = blockIdx.x;
  const int t = threadIdx.x;
  const int w = t >> 6, l = t & 63;
  const int r = l & 15, g = l >> 4;
  const int wr = w >> 1, wc = w & 1;
  const int rsel  = l >> 3;
  const int slotp = (l & 7) ^ (rsel & 7);
  f32x4 acc[4][4] = {};

  if (bid < 576) {
    // ---- QKV GEMM tile
    const int bx = bid % 18, by = bid / 18;
    const int m0 = by * 128;
    const int n0 = bx * 128;
    for (int step = 0; step < 12; ++step) {
      const int k0 = step * 64;
#pragma unroll
      for (int i = 0; i < 4; i++) {
        const int chunk = (i << 2) + w;
        const int row = (chunk << 3) + rsel;
        GLOAD16(Xb + (size_t)(m0 + row) * 768 + k0 + (slotp << 3),
                AsB + (chunk << 10) + (l << 4));
        GLOAD16(Wt + (size_t)(n0 + row) * 768 + k0 + (slotp << 3),
                BsB + (chunk << 10) + (l << 4));
      }
      __syncthreads();
#pragma unroll
      for (int kk = 0; kk < 2; kk++) {
        bf16x8 a[4], b[4];
#pragma unroll
        for (int m = 0; m < 4; m++) {
          const int row = wr * 64 + m * 16 + r;
          a[m] = *(const bf16x8*)(AsB + SWZ(row, kk * 64 + (g << 4)));
        }
#pragma unroll
        for (int n = 0; n < 4; n++) {
          const int row = wc * 64 + n * 16 + r;
          b[n] = *(const bf16x8*)(BsB + SWZ(row, kk * 64 + (g << 4)));
        }
#pragma unroll
        for (int m = 0; m < 4; m++)
#pragma unroll
          for (int n = 0; n < 4; n++)
            acc[m][n] = __builtin_amdgcn_mfma_f32_16x16x32_bf16(a[m], b[n], acc[m][n], 0, 0, 0);
      }
      __syncthreads();
    }
    const int which = bx / 6;
    const int cbase = (bx - which * 6) * 128 + wc * 64;
    unsigned short* dst = which == 0 ? q : (which == 1 ? k : v);
#pragma unroll
    for (int m = 0; m < 4; m++) {
      const int grow = m0 + wr * 64 + m * 16 + g * 4;
#pragma unroll
      for (int n = 0; n < 4; n++) {
        const int c = cbase + n * 16 + r;
        const int head = c >> 6, dim = c & 63;
#pragma unroll
        for (int reg = 0; reg < 4; reg++) {
          const int row = grow + reg;
          const int bb = row >> 10, tok = row & 1023;
          dst[((size_t)(((bb * NH + head) << 10) + tok) << 6) + dim] = f2bf(acc[m][n][reg]);
        }
      }
    }
  } else {
    // ---- 1x1 conv tile + fused BN partials
    const int b2 = bid - 576;
    const int n0 = (b2 & 7) * 128;          // p tile
    const int m0 = ((b2 >> 3) % 6) * 128;   // oc tile
    const int b  = b2 / 48;                 // batch
    const unsigned short* Bb = y1t + ((size_t)b << 18);
    for (int step = 0; step < 4; ++step) {
      const int k0 = step * 64;
#pragma unroll
      for (int i = 0; i < 4; i++) {
        const int chunk = (i << 2) + w;
        const int row = (chunk << 3) + rsel;
        GLOAD16(W2b + (size_t)(m0 + row) * 256 + k0 + (slotp << 3),
                AsB + (chunk << 10) + (l << 4));
        GLOAD16(Bb + (size_t)(n0 + row) * 256 + k0 + (slotp << 3),
                BsB + (chunk << 10) + (l << 4));
      }
      __syncthreads();
#pragma unroll
      for (int kk = 0; kk < 2; kk++) {
        bf16x8 a[4], bfr[4];
#pragma unroll
        for (int m = 0; m < 4; m++) {
          const int row = wr * 64 + m * 16 + r;
          a[m] = *(const bf16x8*)(AsB + SWZ(row, kk * 64 + (g << 4)));
        }
#pragma unroll
        for (int n = 0; n < 4; n++) {
          const int row = wc * 64 + n * 16 + r;
          bfr[n] = *(const bf16x8*)(BsB + SWZ(row, kk * 64 + (g << 4)));
        }
#pragma unroll
        for (int m = 0; m < 4; m++)
#pragma unroll
          for (int n = 0; n < 4; n++)
            acc[m][n] = __builtin_amdgcn_mfma_f32_16x16x32_bf16(a[m], bfr[n], acc[m][n], 0, 0, 0);
      }
      __syncthreads();
    }
    float* Yb = Y2 + (((size_t)b * DMODEL) << 10);
#pragma unroll
    for (int m = 0; m < 4; m++) {
#pragma unroll
      for (int reg = 0; reg < 4; reg++) {
        const int oc = m0 + wr * 64 + m * 16 + g * 4 + reg;
        float s = 0.0f, sq = 0.0f;
#pragma unroll
        for (int n = 0; n < 4; n++) {
          const int p = n0 + wc * 64 + n * 16 + r;
          const float val = acc[m][n][reg];
          Yb[((size_t)oc << 10) + p] = val;
          s += val;
          sq = fmaf(val, val, sq);
        }
        s  += __shfl_xor(s, 1);  sq += __shfl_xor(sq, 1);
        s  += __shfl_xor(s, 2);  sq += __shfl_xor(sq, 2);
        s  += __shfl_xor(s, 4);  sq += __shfl_xor(sq, 4);
        s  += __shfl_xor(s, 8);  sq += __shfl_xor(sq, 8);
        if (r == 0) {
          atomicAdd(&bn_sum[oc], s);
          atomicAdd(&bn_sumsq[oc], sq);
        }
      }
    }
  }
}

// ---------------- K2: flash attention + fused out0 epilogue; tail blocks do out1 BN+ReLU
// blocks [0,768): attention (bh = bid%48, qt = bid/48) ; [768,3840): out1 rows
__global__ __launch_bounds__(256) void k_attn(const unsigned short* __restrict__ qb,
                                              const unsigned short* __restrict__ kb,
                                              const unsigned short* __restrict__ vb,
                                              const float* __restrict__ dm,
                                              const float* __restrict__ y2,
                                              const float* __restrict__ bn_sum,
                                              const float* __restrict__ bn_sumsq,
                                              const float* __restrict__ gamma,
                                              const float* __restrict__ beta,
                                              float* __restrict__ out0,
                                              float* __restrict__ out1) {
  __shared__ __align__(16) unsigned short QsA[4096];
  __shared__ __align__(16) unsigned short KsA[4096];
  __shared__ __align__(16) unsigned short VtA[4096];
  __shared__ __align__(16) unsigned short PsA[4096];
  const int bid = blockIdx.x;
  const int t  = threadIdx.x;
  if (bid >= 768) {
    // ---- out1 = relu(bn(y2)), one (b,c) row per block
    const int row = bid - 768;            // b*768 + c
    const int c = row % DMODEL;
    const float S = bn_sum[c], SQ = bn_sumsq[c];
    const float mean = S * (1.0f / 4096.0f);
    const float var = SQ * (1.0f / 4096.0f) - mean * mean;
    const float rstd = rsqrtf(var + 1e-5f);
    const float sc = gamma[c] * rstd;
    const float sh = fmaf(-mean, sc, beta[c]);
    const float* src = y2 + ((size_t)row << 10) + t * 4;
    float* dst = out1 + ((size_t)row << 10) + t * 4;
    float4 vv = *(const float4*)src;
    vv.x = fmaxf(fmaf(vv.x, sc, sh), 0.0f);
    vv.y = fmaxf(fmaf(vv.y, sc, sh), 0.0f);
    vv.z = fmaxf(fmaf(vv.z, sc, sh), 0.0f);
    vv.w = fmaxf(fmaf(vv.w, sc, sh), 0.0f);
    *(float4*)dst = vv;
    return;
  }
  char* qs = (char*)QsA; char* ks = (char*)KsA;
  char* vt = (char*)VtA; char* ps = (char*)PsA;
  const int bh = bid % 48;
  const int qt = bid / 48;
  const int w = t >> 6, l = t & 63, r = l & 15, g = l >> 4;
  const size_t hbase = (size_t)bh << 16;
  const char* qg = (const char*)(qb + hbase + ((size_t)qt << 12));
  const char* kg = (const char*)(kb + hbase);
  const char* vg = (const char*)(vb + hbase);
  const float* mp = dm + ((size_t)bh << 20) + ((size_t)(qt * 64) << 10);

#pragma unroll
  for (int i = 0; i < 2; i++) {
    int cid = t + (i << 8);
    int row = cid >> 3, slot = cid & 7;
    uint4 val = *(const uint4*)(qg + row * 128 + slot * 16);
    *(uint4*)(qs + SWZ(row, slot * 16)) = val;
  }

  float m_run[4] = {-INFINITY, -INFINITY, -INFINITY, -INFINITY};
  float l_run[4] = {0.0f, 0.0f, 0.0f, 0.0f};
  f32x4 O[4] = {};

  for (int kt = 0; kt < 16; kt++) {
    __syncthreads();
#pragma unroll
    for (int i = 0; i < 2; i++) {
      int cid = t + (i << 8);
      int row = cid >> 3, slot = cid & 7;
      uint4 val = *(const uint4*)(kg + (size_t)(kt * 64 + row) * 128 + slot * 16);
      *(uint4*)(ks + SWZ(row, slot * 16)) = val;
    }
    {
      int j = t & 63, dh = t >> 6;
      const char* vrow = vg + (size_t)(kt * 64 + j) * 128 + dh * 32;
      u16x8 v0 = *(const u16x8*)(vrow);
      u16x8 v1 = *(const u16x8*)(vrow + 16);
#pragma unroll
      for (int e = 0; e < 8; e++) {
        *(unsigned short*)(vt + SWZ(dh * 16 + e, 2 * j))     = v0[e];
        *(unsigned short*)(vt + SWZ(dh * 16 + 8 + e, 2 * j)) = v1[e];
      }
    }
    float md[4][4];
    {
      const float* mr = mp + (size_t)(w * 16 + g * 4) * 1024 + kt * 64 + r;
#pragma unroll
      for (int reg = 0; reg < 4; reg++)
#pragma unroll
        for (int jt = 0; jt < 4; jt++)
          md[reg][jt] = mr[reg * 1024 + jt * 16];
    }
    __syncthreads();

    f32x4 s[4] = {};
    bf16x8 aQ[2];
#pragma unroll
    for (int kc = 0; kc < 2; kc++)
      aQ[kc] = *(const bf16x8*)(qs + SWZ(w * 16 + r, kc * 64 + g * 16));
#pragma unroll
    for (int jt = 0; jt < 4; jt++) {
#pragma unroll
      for (int kc = 0; kc < 2; kc++) {
        bf16x8 bK = *(const bf16x8*)(ks + SWZ(jt * 16 + r, kc * 64 + g * 16));
        s[jt] = __builtin_amdgcn_mfma_f32_16x16x32_bf16(aQ[kc], bK, s[jt], 0, 0, 0);
      }
    }
    float sv[4][4];
#pragma unroll
    for (int jt = 0; jt < 4; jt++)
#pragma unroll
      for (int reg = 0; reg < 4; reg++)
        sv[jt][reg] = s[jt][reg] * 0.125f + (md[reg][jt] < 0.1f ? -1e12f : 0.0f);

    float alpha[4];
#pragma unroll
    for (int reg = 0; reg < 4; reg++) {
      float mt = fmaxf(fmaxf(sv[0][reg], sv[1][reg]), fmaxf(sv[2][reg], sv[3][reg]));
      mt = fmaxf(mt, __shfl_xor(mt, 1));
      mt = fmaxf(mt, __shfl_xor(mt, 2));
      mt = fmaxf(mt, __shfl_xor(mt, 4));
      mt = fmaxf(mt, __shfl_xor(mt, 8));
      float mn = fmaxf(m_run[reg], mt);
      alpha[reg] = __expf(m_run[reg] - mn);
      m_run[reg] = mn;
    }
#pragma unroll
    for (int reg = 0; reg < 4; reg++) {
      int row = w * 16 + g * 4 + reg;
      float ps_ = 0.0f;
#pragma unroll
      for (int jt = 0; jt < 4; jt++) {
        float p = __expf(sv[jt][reg] - m_run[reg]);
        ps_ += p;
        *(unsigned short*)(ps + SWZ(row, 2 * (jt * 16 + r))) = f2bf(p);
      }
      ps_ += __shfl_xor(ps_, 1);
      ps_ += __shfl_xor(ps_, 2);
      ps_ += __shfl_xor(ps_, 4);
      ps_ += __shfl_xor(ps_, 8);
      l_run[reg] = l_run[reg] * alpha[reg] + ps_;
    }
#pragma unroll
    for (int dt = 0; dt < 4; dt++)
#pragma unroll
      for (int reg = 0; reg < 4; reg++)
        O[dt][reg] *= alpha[reg];
    asm volatile("s_waitcnt lgkmcnt(0)" ::: "memory");
    __builtin_amdgcn_sched_barrier(0);
#pragma unroll
    for (int kc = 0; kc < 2; kc++) {
      bf16x8 aP = *(const bf16x8*)(ps + SWZ(w * 16 + r, kc * 64 + g * 16));
#pragma unroll
      for (int dt = 0; dt < 4; dt++) {
        bf16x8 bV = *(const bf16x8*)(vt + SWZ(dt * 16 + r, kc * 64 + g * 16));
        O[dt] = __builtin_amdgcn_mfma_f32_16x16x32_bf16(aP, bV, O[dt], 0, 0, 0);
      }
    }
  }
  // ---- epilogue: out0 = attn_out + relu(bn(y2^T)) for this exact tile
  const int bb = bh / NH, hh = bh % NH;
  float inv[4];
#pragma unroll
  for (int reg = 0; reg < 4; reg++) inv[reg] = 1.0f / l_run[reg];
  float scv[4], shv[4];
#pragma unroll
  for (int dt = 0; dt < 4; dt++) {
    const int c = hh * 64 + dt * 16 + r;
    const float S = bn_sum[c], SQ = bn_sumsq[c];
    const float mean = S * (1.0f / 4096.0f);
    const float var = SQ * (1.0f / 4096.0f) - mean * mean;
    const float rstd = rsqrtf(var + 1e-5f);
    const float sc = gamma[c] * rstd;
    scv[dt] = sc;
    shv[dt] = fmaf(-mean, sc, beta[c]);
  }
  const int prow = qt * 64 + w * 16 + g * 4;
  const float* y2p = y2 + (((size_t)(bb * DMODEL + hh * 64 + r)) << 10) + prow;
  float4 yq[4];
#pragma unroll
  for (int dt = 0; dt < 4; dt++)
    yq[dt] = *(const float4*)(y2p + ((size_t)dt << 14));
  float* op = out0 + ((size_t)(bb * 1024 + prow)) * 768 + hh * 64 + r;
#pragma unroll
  for (int reg = 0; reg < 4; reg++)
#pragma unroll
    for (int dt = 0; dt < 4; dt++) {
      const float yv = (&yq[dt].x)[reg];
      const float ytok = fmaxf(fmaf(yv, scv[dt], shv[dt]), 0.0f);
      op[(size_t)reg * 768 + dt * 16] = fmaf(O[dt][reg], inv[reg], ytok);
    }
}

extern "C" void kernel_launch(void* const* d_in, const int* in_sizes, int n_in,
                              void* d_out, int out_size, void* d_ws, size_t ws_size,
                              hipStream_t stream) {
  (void)in_sizes; (void)n_in; (void)out_size; (void)ws_size;
  const float* x    = (const float*)d_in[0];
  const float* y    = (const float*)d_in[1];
  const float* dm   = (const float*)d_in[2];
  const float* wqkv = (const float*)d_in[3];
  const float* w1   = (const float*)d_in[4];
  const float* w2   = (const float*)d_in[5];
  const float* gam  = (const float*)d_in[6];
  const float* bet  = (const float*)d_in[7];
  float* out0 = (float*)d_out;
  float* out1 = out0 + (size_t)B_ * NTOK * DMODEL;

  char* wsb = (char*)d_ws;
  unsigned short* Xb  = (unsigned short*)wsb;
  unsigned short* Wtb = (unsigned short*)(wsb + 6291456);
  unsigned short* W2b = (unsigned short*)(wsb + 9830400);
  unsigned short* qb  = (unsigned short*)(wsb + 10223616);
  unsigned short* kb  = (unsigned short*)(wsb + 16515072);
  unsigned short* vb  = (unsigned short*)(wsb + 22806528);
  unsigned short* y1t = (unsigned short*)(wsb + 29097984);
  float* y2 = (float*)(wsb + 31195136);
  float* y1 = (float*)(wsb + 35389440);
  float* bnacc = (float*)(wsb + 43778048);
  float* bn_sum = bnacc;
  float* bn_sumsq = bnacc + 768;

  k_cvt<<<dim3(4385), 256, 0, stream>>>(x, wqkv, w2, y, w1, Xb, Wtb, W2b, y1, bnacc);
  k_trans<<<dim3(16, 4, B_), 256, 0, stream>>>(y1, y1t);
  k_mm<<<dim3(768), 256, 0, stream>>>(Xb, Wtb, qb, kb, vb, W2b, y1t, y2, bn_sum, bn_sumsq);
  k_attn<<<dim3(3840), 256, 0, stream>>>(qb, kb, vb, dm, y2, bn_sum, bn_sumsq, gam, bet, out0, out1);
}